// Round 1
// baseline (340.361 us; speedup 1.0000x reference)
//
#include <hip/hip_runtime.h>

typedef unsigned short u16;
typedef unsigned int u32;
typedef float f32x4 __attribute__((ext_vector_type(4)));
typedef __bf16 bf16x8 __attribute__((ext_vector_type(8)));
typedef u32 u32x4 __attribute__((ext_vector_type(4)));
typedef u16 u16x4 __attribute__((ext_vector_type(4)));

#define NB 16
#define NSEQ 1024
#define NL 120
#define NLP 128
#define NC 1024
#define NH 16
#define NDH 64

__device__ __forceinline__ u16 f2bf(float f) {
  u32 u = __float_as_uint(f);
  return (u16)((u + 0x7fffu + ((u >> 16) & 1u)) >> 16);  // RNE
}

__device__ __forceinline__ void gld_lds16(const void* g, void* l) {
  __builtin_amdgcn_global_load_lds(
      (const __attribute__((address_space(1))) void*)g,
      (__attribute__((address_space(3))) void*)l, 16, 0, 0);
}

__global__ __launch_bounds__(256) void cast_f32_bf16(const float* __restrict__ src,
                                                     u16* __restrict__ dst) {
  size_t i = ((size_t)blockIdx.x * 256 + threadIdx.x) * 4;
  f32x4 v = *(const f32x4*)(src + i);
  u16x4 o;
  o.x = f2bf(v.x); o.y = f2bf(v.y); o.z = f2bf(v.z); o.w = f2bf(v.w);
  *(u16x4*)(dst + i) = o;
}

// C = A(MxK) * Bt(NxK)^T + bias, m97 structure: 128x128 tile, BK=32, 4 waves,
// each wave a 64x64 quadrant of 4x4 16x16x32 bf16 MFMA subtiles.
template <bool OUT_F32>
__global__ __launch_bounds__(256) void gemm_bt(
    const u16* __restrict__ A, const u16* __restrict__ Bt,
    const float* __restrict__ bias, void* __restrict__ Cout,
    int M, int Nn, int K) {
  __shared__ u16 As[128 * 32];
  __shared__ u16 Bs[128 * 32];
  const int nt = Nn >> 7;
  const int bm = (int)blockIdx.x / nt;
  const int bn = (int)blockIdx.x % nt;
  const int m0 = bm << 7, n0 = bn << 7;
  const int tid = threadIdx.x;
  const int w = tid >> 6, lane = tid & 63;
  const int wm = (w & 1) << 6, wn = (w >> 1) << 6;
  const int quad = lane >> 4, l15 = lane & 15;

  f32x4 acc[4][4];
#pragma unroll
  for (int i = 0; i < 4; ++i)
#pragma unroll
    for (int j = 0; j < 4; ++j) acc[i][j] = (f32x4){0.f, 0.f, 0.f, 0.f};

  // staging: 16B/thread, 2 rounds each for A and B; LDS dst = wave base + lane*16
  const int r0 = tid >> 2;
  const int cb = (tid & 3) << 3;
  const u16* aP = A + (size_t)(m0 + r0) * K + cb;
  const u16* bP = Bt + (size_t)(n0 + r0) * K + cb;
  u16* asDst = &As[r0 * 32 + cb];
  u16* bsDst = &Bs[r0 * 32 + cb];

  for (int k0 = 0; k0 < K; k0 += 32) {
    __syncthreads();
    gld_lds16(aP + k0, asDst);
    gld_lds16(aP + (size_t)64 * K + k0, asDst + 64 * 32);
    gld_lds16(bP + k0, bsDst);
    gld_lds16(bP + (size_t)64 * K + k0, bsDst + 64 * 32);
    __syncthreads();

    bf16x8 af[4], bfr[4];
#pragma unroll
    for (int i = 0; i < 4; ++i)
      af[i] = *(const bf16x8*)&As[(wm + i * 16 + l15) * 32 + quad * 8];
#pragma unroll
    for (int j = 0; j < 4; ++j)
      bfr[j] = *(const bf16x8*)&Bs[(wn + j * 16 + l15) * 32 + quad * 8];
#pragma unroll
    for (int i = 0; i < 4; ++i)
#pragma unroll
      for (int j = 0; j < 4; ++j)
        acc[i][j] =
            __builtin_amdgcn_mfma_f32_16x16x32_bf16(af[i], bfr[j], acc[i][j], 0, 0, 0);
  }

  // epilogue: C/D layout col=lane&15, row=quad*4+reg  [verified m89/m91]
#pragma unroll
  for (int j = 0; j < 4; ++j) {
    const int col = n0 + wn + j * 16 + l15;
    const float bv = bias[col];
#pragma unroll
    for (int i = 0; i < 4; ++i) {
      const int row = m0 + wm + i * 16 + quad * 4;
#pragma unroll
      for (int r = 0; r < 4; ++r) {
        const float v = acc[i][j][r] + bv;
        if (OUT_F32)
          ((float*)Cout)[(size_t)(row + r) * Nn + col] = v;
        else
          ((u16*)Cout)[(size_t)(row + r) * Nn + col] = f2bf(v);
      }
    }
  }
}

// one block per (b,h); K/V/mask staged in LDS once; 4 waves x 16 queries/iter x 16 iters
__global__ __launch_bounds__(256) void attn(
    const u16* __restrict__ Qb, const u16* __restrict__ KVb,
    const int* __restrict__ mask, u16* __restrict__ Ob) {
  __shared__ u16 Ks[NLP * NDH];    // [key][dh], keys >= NL zeroed
  __shared__ u16 Vt[NDH * NLP];    // [dh][key], keys >= NL zeroed
  __shared__ float mb[NLP];        // additive mask bias
  __shared__ u16 pb[4][16 * NLP];  // per-wave P buffer (A-layout row-major)

  const int b = (int)blockIdx.x >> 4;
  const int h = (int)blockIdx.x & 15;
  const int tid = threadIdx.x;
  const int w = tid >> 6, lane = tid & 63;
  const int quad = lane >> 4, l15 = lane & 15;
  const u16* kvbase = KVb + (size_t)b * NL * 2 * NC;

  for (int i = tid; i < NLP * 8; i += 256) {
    const int l = i >> 3, c8 = (i & 7) * 8;
    u32x4 z = {0u, 0u, 0u, 0u};
    u32x4 v = (l < NL) ? *(const u32x4*)(kvbase + (size_t)l * 2 * NC + h * NDH + c8) : z;
    *(u32x4*)&Ks[l * NDH + c8] = v;
  }
  u16* vstage = &pb[0][0];  // scratch for coalesced V rows before transpose
  for (int i = tid; i < NL * 8; i += 256) {
    const int l = i >> 3, c8 = (i & 7) * 8;
    *(u32x4*)&vstage[l * NDH + c8] =
        *(const u32x4*)(kvbase + (size_t)l * 2 * NC + NC + h * NDH + c8);
  }
  for (int i = tid; i < NLP; i += 256)
    mb[i] = (i < NL && mask[b * NL + i] != 0) ? 0.0f : -1e30f;
  __syncthreads();
  for (int i = tid; i < NDH * NLP; i += 256) {
    const int d = i >> 7, l = i & 127;
    Vt[d * NLP + l] = (l < NL) ? vstage[l * NDH + d] : (u16)0;
  }
  __syncthreads();

  const float scale = 0.125f;  // 64^-0.5
  for (int it = 0; it < 16; ++it) {
    const int q0 = it * 64 + w * 16;
    // A-frag of Q from global: A[m=lane&15][k=quad*8+j]
    const u16* qptr = Qb + (size_t)(b * NSEQ + q0 + l15) * NC + h * NDH + quad * 8;
    const bf16x8 a0 = *(const bf16x8*)qptr;
    const bf16x8 a1 = *(const bf16x8*)(qptr + 32);

    f32x4 s[8];
#pragma unroll
    for (int kt = 0; kt < 8; ++kt) {
      const u16* kb = &Ks[(kt * 16 + l15) * NDH + quad * 8];
      const bf16x8 b0 = *(const bf16x8*)kb;
      const bf16x8 b1 = *(const bf16x8*)(kb + 32);
      f32x4 t = {0.f, 0.f, 0.f, 0.f};
      t = __builtin_amdgcn_mfma_f32_16x16x32_bf16(a0, b0, t, 0, 0, 0);
      t = __builtin_amdgcn_mfma_f32_16x16x32_bf16(a1, b1, t, 0, 0, 0);
      s[kt] = t;
    }
#pragma unroll
    for (int kt = 0; kt < 8; ++kt) {
      const float mbv = mb[kt * 16 + l15];
#pragma unroll
      for (int r = 0; r < 4; ++r) s[kt][r] = s[kt][r] * scale + mbv;
    }
    // register softmax: row (quad*4+r) lives in the quad's 16 lanes across 8 subtiles
    float sum[4];
#pragma unroll
    for (int r = 0; r < 4; ++r) {
      float m = s[0][r];
#pragma unroll
      for (int kt = 1; kt < 8; ++kt) m = fmaxf(m, s[kt][r]);
      m = fmaxf(m, __shfl_xor(m, 1));
      m = fmaxf(m, __shfl_xor(m, 2));
      m = fmaxf(m, __shfl_xor(m, 4));
      m = fmaxf(m, __shfl_xor(m, 8));
      float su = 0.f;
#pragma unroll
      for (int kt = 0; kt < 8; ++kt) {
        s[kt][r] = __expf(s[kt][r] - m);
        su += s[kt][r];
      }
      su += __shfl_xor(su, 1);
      su += __shfl_xor(su, 2);
      su += __shfl_xor(su, 4);
      su += __shfl_xor(su, 8);
      sum[r] = su;
    }
#pragma unroll
    for (int r = 0; r < 4; ++r) {
      const float inv = 1.0f / sum[r];
#pragma unroll
      for (int kt = 0; kt < 8; ++kt)
        pb[w][(quad * 4 + r) * NLP + kt * 16 + l15] = f2bf(s[kt][r] * inv);
    }
    // PV: P(16x128) x V(128x64); same-wave LDS ops are in-order, no barrier needed
#pragma unroll
    for (int ntl = 0; ntl < 4; ++ntl) {
      f32x4 o = {0.f, 0.f, 0.f, 0.f};
#pragma unroll
      for (int kt = 0; kt < 4; ++kt) {
        const bf16x8 pa = *(const bf16x8*)&pb[w][l15 * NLP + kt * 32 + quad * 8];
        const bf16x8 vb = *(const bf16x8*)&Vt[(ntl * 16 + l15) * NLP + kt * 32 + quad * 8];
        o = __builtin_amdgcn_mfma_f32_16x16x32_bf16(pa, vb, o, 0, 0, 0);
      }
#pragma unroll
      for (int r = 0; r < 4; ++r)
        Ob[(size_t)(b * NSEQ + q0 + quad * 4 + r) * NC + h * NDH + ntl * 16 + l15] =
            f2bf(o[r]);
    }
  }
}

extern "C" void kernel_launch(void* const* d_in, const int* in_sizes, int n_in,
                              void* d_out, int out_size, void* d_ws, size_t ws_size,
                              hipStream_t stream) {
  const float* x = (const float*)d_in[0];
  const float* cond = (const float*)d_in[1];
  const int* mask = (const int*)d_in[2];
  const float* Wq = (const float*)d_in[3];
  const float* bq = (const float*)d_in[4];
  const float* Wkv = (const float*)d_in[5];
  const float* bkv = (const float*)d_in[6];
  const float* Wp = (const float*)d_in[7];
  const float* bp = (const float*)d_in[8];

  // workspace layout (87,293,952 B total; Ob aliases xb — x dead after Q-proj)
  char* ws = (char*)d_ws;
  u16* xb = (u16*)(ws + 0);            // 33,554,432
  u16* condb = (u16*)(ws + 33554432);  //  3,932,160
  u16* Wqb = (u16*)(ws + 37486592);    //  2,097,152
  u16* Wkvb = (u16*)(ws + 39583744);   //  4,194,304
  u16* Wpb = (u16*)(ws + 43778048);    //  2,097,152
  u16* Qb = (u16*)(ws + 45875200);     // 33,554,432
  u16* KVb = (u16*)(ws + 79429632);    //  7,864,320
  u16* Ob = xb;

  cast_f32_bf16<<<16384, 256, 0, stream>>>(x, xb);
  cast_f32_bf16<<<1920, 256, 0, stream>>>(cond, condb);
  cast_f32_bf16<<<1024, 256, 0, stream>>>(Wq, Wqb);
  cast_f32_bf16<<<2048, 256, 0, stream>>>(Wkv, Wkvb);
  cast_f32_bf16<<<1024, 256, 0, stream>>>(Wp, Wpb);

  gemm_bt<false><<<128 * 8, 256, 0, stream>>>(xb, Wqb, bq, Qb, 16384, 1024, 1024);
  gemm_bt<false><<<15 * 16, 256, 0, stream>>>(condb, Wkvb, bkv, KVb, 1920, 2048, 1024);
  attn<<<256, 256, 0, stream>>>(Qb, KVb, mask, Ob);
  gemm_bt<true><<<128 * 8, 256, 0, stream>>>(Ob, Wpb, bp, d_out, 16384, 1024, 1024);
}

// Round 2
// 331.580 us; speedup vs baseline: 1.0265x; 1.0265x over previous
//
#include <hip/hip_runtime.h>

typedef unsigned short u16;
typedef unsigned int u32;
typedef float f32x4 __attribute__((ext_vector_type(4)));
typedef __bf16 bf16x8 __attribute__((ext_vector_type(8)));
typedef u32 u32x4 __attribute__((ext_vector_type(4)));
typedef u16 u16x4 __attribute__((ext_vector_type(4)));

#define NB 16
#define NSEQ 1024
#define NL 120
#define NLP 128
#define NC 1024
#define NH 16
#define NDH 64

__device__ __forceinline__ u16 f2bf(float f) {
  u32 u = __float_as_uint(f);
  return (u16)((u + 0x7fffu + ((u >> 16) & 1u)) >> 16);  // RNE
}

__device__ __forceinline__ void gld_lds16(const void* g, void* l) {
  __builtin_amdgcn_global_load_lds(
      (const __attribute__((address_space(1))) void*)g,
      (__attribute__((address_space(3))) void*)l, 16, 0, 0);
}

// one launch casts all five fp32 tensors to bf16; segment bounds compile-time
// (block counts: x 16384 | cond 1920 | Wq 1024 | Wkv 2048 | Wp 1024)
__global__ __launch_bounds__(256) void cast_all(
    const float* __restrict__ x, u16* __restrict__ xb,
    const float* __restrict__ cond, u16* __restrict__ condb,
    const float* __restrict__ Wq, u16* __restrict__ Wqb,
    const float* __restrict__ Wkv, u16* __restrict__ Wkvb,
    const float* __restrict__ Wp, u16* __restrict__ Wpb) {
  int bk = blockIdx.x;
  const float* src;
  u16* dst;
  if (bk < 16384) { src = x; dst = xb; }
  else if (bk < 18304) { src = cond; dst = condb; bk -= 16384; }
  else if (bk < 19328) { src = Wq; dst = Wqb; bk -= 18304; }
  else if (bk < 21376) { src = Wkv; dst = Wkvb; bk -= 19328; }
  else { src = Wp; dst = Wpb; bk -= 21376; }
  size_t i = ((size_t)bk * 256 + threadIdx.x) * 4;
  f32x4 v = *(const f32x4*)(src + i);
  u16x4 o;
  o.x = f2bf(v.x); o.y = f2bf(v.y); o.z = f2bf(v.z); o.w = f2bf(v.w);
  *(u16x4*)(dst + i) = o;
}

// C = A(MxK) * Bt(NxK)^T + bias, m97 structure: 128x128 tile, BK=32, 4 waves.
// Block mapping bm = blockIdx % mt: same-bm blocks are congruent mod 8 ->
// same XCD (round-robin heuristic) -> A-slab reused out of that XCD's L2.
template <bool OUT_F32>
__global__ __launch_bounds__(256) void gemm_bt(
    const u16* __restrict__ A, const u16* __restrict__ Bt,
    const float* __restrict__ bias, void* __restrict__ Cout,
    int M, int Nn, int K) {
  __shared__ u16 As[128 * 32];
  __shared__ u16 Bs[128 * 32];
  const int mt = M >> 7;
  const int bm = (int)blockIdx.x % mt;
  const int bn = (int)blockIdx.x / mt;
  const int m0 = bm << 7, n0 = bn << 7;
  const int tid = threadIdx.x;
  const int w = tid >> 6, lane = tid & 63;
  const int wm = (w & 1) << 6, wn = (w >> 1) << 6;
  const int quad = lane >> 4, l15 = lane & 15;

  f32x4 acc[4][4];
#pragma unroll
  for (int i = 0; i < 4; ++i)
#pragma unroll
    for (int j = 0; j < 4; ++j) acc[i][j] = (f32x4){0.f, 0.f, 0.f, 0.f};

  // staging: 16B/thread, 2 rounds each for A and B; LDS dst = wave base + lane*16
  const int r0 = tid >> 2;
  const int cb = (tid & 3) << 3;
  const u16* aP = A + (size_t)(m0 + r0) * K + cb;
  const u16* bP = Bt + (size_t)(n0 + r0) * K + cb;
  u16* asDst = &As[r0 * 32 + cb];
  u16* bsDst = &Bs[r0 * 32 + cb];

  for (int k0 = 0; k0 < K; k0 += 32) {
    __syncthreads();
    gld_lds16(aP + k0, asDst);
    gld_lds16(aP + (size_t)64 * K + k0, asDst + 64 * 32);
    gld_lds16(bP + k0, bsDst);
    gld_lds16(bP + (size_t)64 * K + k0, bsDst + 64 * 32);
    __syncthreads();

    bf16x8 af[4], bfr[4];
#pragma unroll
    for (int i = 0; i < 4; ++i)
      af[i] = *(const bf16x8*)&As[(wm + i * 16 + l15) * 32 + quad * 8];
#pragma unroll
    for (int j = 0; j < 4; ++j)
      bfr[j] = *(const bf16x8*)&Bs[(wn + j * 16 + l15) * 32 + quad * 8];
#pragma unroll
    for (int i = 0; i < 4; ++i)
#pragma unroll
      for (int j = 0; j < 4; ++j)
        acc[i][j] =
            __builtin_amdgcn_mfma_f32_16x16x32_bf16(af[i], bfr[j], acc[i][j], 0, 0, 0);
  }

  // epilogue: C/D layout col=lane&15, row=quad*4+reg  [verified m89/m91]
#pragma unroll
  for (int j = 0; j < 4; ++j) {
    const int col = n0 + wn + j * 16 + l15;
    const float bv = bias[col];
#pragma unroll
    for (int i = 0; i < 4; ++i) {
      const int row = m0 + wm + i * 16 + quad * 4;
#pragma unroll
      for (int r = 0; r < 4; ++r) {
        const float v = acc[i][j][r] + bv;
        if (OUT_F32)
          ((float*)Cout)[(size_t)(row + r) * Nn + col] = v;
        else
          ((u16*)Cout)[(size_t)(row + r) * Nn + col] = f2bf(v);
      }
    }
  }
}

// one block per (b,h,chunk-of-256-queries); K/V/mask staged in LDS once;
// 4 waves x 16 queries/iter x 4 iters
__global__ __launch_bounds__(256) void attn(
    const u16* __restrict__ Qb, const u16* __restrict__ KVb,
    const int* __restrict__ mask, u16* __restrict__ Ob) {
  __shared__ u16 Ks[NLP * NDH];    // [key][dh], keys >= NL zeroed
  __shared__ u16 Vt[NDH * NLP];    // [dh][key], keys >= NL zeroed
  __shared__ float mb[NLP];        // additive mask bias
  __shared__ u16 pb[4][16 * NLP];  // per-wave P buffer (A-layout row-major)

  const int chunk = (int)blockIdx.x & 3;
  const int h = ((int)blockIdx.x >> 2) & 15;
  const int b = (int)blockIdx.x >> 6;
  const int tid = threadIdx.x;
  const int w = tid >> 6, lane = tid & 63;
  const int quad = lane >> 4, l15 = lane & 15;
  const u16* kvbase = KVb + (size_t)b * NL * 2 * NC;

  for (int i = tid; i < NLP * 8; i += 256) {
    const int l = i >> 3, c8 = (i & 7) * 8;
    u32x4 z = {0u, 0u, 0u, 0u};
    u32x4 v = (l < NL) ? *(const u32x4*)(kvbase + (size_t)l * 2 * NC + h * NDH + c8) : z;
    *(u32x4*)&Ks[l * NDH + c8] = v;
  }
  u16* vstage = &pb[0][0];  // scratch for coalesced V rows before transpose
  for (int i = tid; i < NL * 8; i += 256) {
    const int l = i >> 3, c8 = (i & 7) * 8;
    *(u32x4*)&vstage[l * NDH + c8] =
        *(const u32x4*)(kvbase + (size_t)l * 2 * NC + NC + h * NDH + c8);
  }
  for (int i = tid; i < NLP; i += 256)
    mb[i] = (i < NL && mask[b * NL + i] != 0) ? 0.0f : -1e30f;
  __syncthreads();
  for (int i = tid; i < NDH * NLP; i += 256) {
    const int d = i >> 7, l = i & 127;
    Vt[d * NLP + l] = (l < NL) ? vstage[l * NDH + d] : (u16)0;
  }
  __syncthreads();

  const float scale = 0.125f;  // 64^-0.5
  for (int it = 0; it < 4; ++it) {
    const int q0 = chunk * 256 + it * 64 + w * 16;
    // A-frag of Q from global: A[m=lane&15][k=quad*8+j]
    const u16* qptr = Qb + (size_t)(b * NSEQ + q0 + l15) * NC + h * NDH + quad * 8;
    const bf16x8 a0 = *(const bf16x8*)qptr;
    const bf16x8 a1 = *(const bf16x8*)(qptr + 32);

    f32x4 s[8];
#pragma unroll
    for (int kt = 0; kt < 8; ++kt) {
      const u16* kb = &Ks[(kt * 16 + l15) * NDH + quad * 8];
      const bf16x8 b0 = *(const bf16x8*)kb;
      const bf16x8 b1 = *(const bf16x8*)(kb + 32);
      f32x4 t = {0.f, 0.f, 0.f, 0.f};
      t = __builtin_amdgcn_mfma_f32_16x16x32_bf16(a0, b0, t, 0, 0, 0);
      t = __builtin_amdgcn_mfma_f32_16x16x32_bf16(a1, b1, t, 0, 0, 0);
      s[kt] = t;
    }
#pragma unroll
    for (int kt = 0; kt < 8; ++kt) {
      const float mbv = mb[kt * 16 + l15];
#pragma unroll
      for (int r = 0; r < 4; ++r) s[kt][r] = s[kt][r] * scale + mbv;
    }
    // register softmax: row (quad*4+r) lives in the quad's 16 lanes across 8 subtiles
    float sum[4];
#pragma unroll
    for (int r = 0; r < 4; ++r) {
      float m = s[0][r];
#pragma unroll
      for (int kt = 1; kt < 8; ++kt) m = fmaxf(m, s[kt][r]);
      m = fmaxf(m, __shfl_xor(m, 1));
      m = fmaxf(m, __shfl_xor(m, 2));
      m = fmaxf(m, __shfl_xor(m, 4));
      m = fmaxf(m, __shfl_xor(m, 8));
      float su = 0.f;
#pragma unroll
      for (int kt = 0; kt < 8; ++kt) {
        s[kt][r] = __expf(s[kt][r] - m);
        su += s[kt][r];
      }
      su += __shfl_xor(su, 1);
      su += __shfl_xor(su, 2);
      su += __shfl_xor(su, 4);
      su += __shfl_xor(su, 8);
      sum[r] = su;
    }
#pragma unroll
    for (int r = 0; r < 4; ++r) {
      const float inv = 1.0f / sum[r];
#pragma unroll
      for (int kt = 0; kt < 8; ++kt)
        pb[w][(quad * 4 + r) * NLP + kt * 16 + l15] = f2bf(s[kt][r] * inv);
    }
    // PV: P(16x128) x V(128x64); same-wave LDS ops are in-order, no barrier needed
#pragma unroll
    for (int ntl = 0; ntl < 4; ++ntl) {
      f32x4 o = {0.f, 0.f, 0.f, 0.f};
#pragma unroll
      for (int kt = 0; kt < 4; ++kt) {
        const bf16x8 pa = *(const bf16x8*)&pb[w][l15 * NLP + kt * 32 + quad * 8];
        const bf16x8 vb = *(const bf16x8*)&Vt[(ntl * 16 + l15) * NLP + kt * 32 + quad * 8];
        o = __builtin_amdgcn_mfma_f32_16x16x32_bf16(pa, vb, o, 0, 0, 0);
      }
#pragma unroll
      for (int r = 0; r < 4; ++r)
        Ob[(size_t)(b * NSEQ + q0 + quad * 4 + r) * NC + h * NDH + ntl * 16 + l15] =
            f2bf(o[r]);
    }
  }
}

extern "C" void kernel_launch(void* const* d_in, const int* in_sizes, int n_in,
                              void* d_out, int out_size, void* d_ws, size_t ws_size,
                              hipStream_t stream) {
  const float* x = (const float*)d_in[0];
  const float* cond = (const float*)d_in[1];
  const int* mask = (const int*)d_in[2];
  const float* Wq = (const float*)d_in[3];
  const float* bq = (const float*)d_in[4];
  const float* Wkv = (const float*)d_in[5];
  const float* bkv = (const float*)d_in[6];
  const float* Wp = (const float*)d_in[7];
  const float* bp = (const float*)d_in[8];

  // workspace layout (87,293,952 B total; Ob aliases xb — x dead after Q-proj)
  char* ws = (char*)d_ws;
  u16* xb = (u16*)(ws + 0);            // 33,554,432
  u16* condb = (u16*)(ws + 33554432);  //  3,932,160
  u16* Wqb = (u16*)(ws + 37486592);    //  2,097,152
  u16* Wkvb = (u16*)(ws + 39583744);   //  4,194,304
  u16* Wpb = (u16*)(ws + 43778048);    //  2,097,152
  u16* Qb = (u16*)(ws + 45875200);     // 33,554,432
  u16* KVb = (u16*)(ws + 79429632);    //  7,864,320
  u16* Ob = xb;

  cast_all<<<22400, 256, 0, stream>>>(x, xb, cond, condb, Wq, Wqb, Wkv, Wkvb, Wp, Wpb);

  gemm_bt<false><<<128 * 8, 256, 0, stream>>>(xb, Wqb, bq, Qb, 16384, 1024, 1024);
  gemm_bt<false><<<15 * 16, 256, 0, stream>>>(condb, Wkvb, bkv, KVb, 1920, 2048, 1024);
  attn<<<1024, 256, 0, stream>>>(Qb, KVb, mask, Ob);
  gemm_bt<true><<<128 * 8, 256, 0, stream>>>(Ob, Wpb, bp, d_out, 16384, 1024, 1024);
}